// Round 6
// baseline (383.691 us; speedup 1.0000x reference)
//
#include <hip/hip_runtime.h>
#include <hip/hip_bf16.h>
#include <math.h>

// Problem constants
#define T_SEQ 4096
#define C_DIM 768
#define N_HEADS 12
#define D_HEAD 64
#define F_DIM 3072   // 4*C
#define EPS 1e-5f
#define QSCALE 0.18033688011112042f   // (1/8) * log2(e): softmax done in base-2

typedef __attribute__((ext_vector_type(8))) short short8;
typedef __attribute__((ext_vector_type(4))) float f32x4;

// async global->LDS, 16B per lane. LDS dest must be wave-uniform base (HW adds lane*16).
__device__ __forceinline__ void gload_lds16(const void* g, void* lds) {
    __builtin_amdgcn_global_load_lds(
        (const __attribute__((address_space(1))) unsigned int*)g,
        (__attribute__((address_space(3))) unsigned int*)lds, 16, 0, 0);
}

// ---------------------------------------------------------------------------
// Fused square-weight transpose + bf16 cast (Wq/Wk/Wv/Wo in one launch).
// W[768][768] f32 -> Wt[768][768] bf16 transposed. blockIdx.z selects matrix.
// ---------------------------------------------------------------------------
__launch_bounds__(256)
__global__ void transpose_w4(const float* __restrict__ Wq, const float* __restrict__ Wk,
                             const float* __restrict__ Wv, const float* __restrict__ Wo,
                             __hip_bfloat16* __restrict__ Wqkv_t,
                             __hip_bfloat16* __restrict__ Wo_t) {
    __shared__ float tile[64][65];
    const int z = blockIdx.z;
    const float* W = (z == 0) ? Wq : (z == 1) ? Wk : (z == 2) ? Wv : Wo;
    __hip_bfloat16* Wt = (z < 3) ? (Wqkv_t + (size_t)z * C_DIM * C_DIM) : Wo_t;
    const int k0 = blockIdx.x * 64;
    const int n0 = blockIdx.y * 64;
    const int tid = threadIdx.x;
    const int c = tid & 63;
    const int r0 = (tid >> 6) * 16;
    #pragma unroll
    for (int i = 0; i < 16; ++i)
        tile[r0 + i][c] = W[(size_t)(k0 + r0 + i) * C_DIM + n0 + c];
    __syncthreads();
    #pragma unroll
    for (int i = 0; i < 16; ++i)
        Wt[(size_t)(n0 + r0 + i) * C_DIM + k0 + c] = __float2bfloat16(tile[c][r0 + i]);
}

// General transpose for W1/W2.
__launch_bounds__(256)
__global__ void transpose_w(const float* __restrict__ W, __hip_bfloat16* __restrict__ Wt,
                            int K, int N) {
    __shared__ float tile[64][65];
    const int k0 = blockIdx.x * 64;
    const int n0 = blockIdx.y * 64;
    const int tid = threadIdx.x;
    const int c = tid & 63;
    const int r0 = (tid >> 6) * 16;
    #pragma unroll
    for (int i = 0; i < 16; ++i)
        tile[r0 + i][c] = W[(size_t)(k0 + r0 + i) * N + n0 + c];
    __syncthreads();
    #pragma unroll
    for (int i = 0; i < 16; ++i)
        Wt[(size_t)(n0 + r0 + i) * K + k0 + c] = __float2bfloat16(tile[c][r0 + i]);
}

__launch_bounds__(256)
__global__ void concat_bias(const float* __restrict__ bq, const float* __restrict__ bk,
                            const float* __restrict__ bv, float* __restrict__ o) {
    const int i = blockIdx.x * 256 + threadIdx.x;
    if (i < C_DIM) {
        o[i] = bq[i];
        o[C_DIM + i] = bk[i];
        o[2 * C_DIM + i] = bv[i];
    }
}

__launch_bounds__(256)
__global__ void f32_to_bf16_vec(const float* __restrict__ in, __hip_bfloat16* __restrict__ out,
                                int n4) {
    const int i = blockIdx.x * 256 + threadIdx.x;
    if (i < n4) {
        const float4 v = *reinterpret_cast<const float4*>(&in[(size_t)i * 4]);
        ushort4 u;
        u.x = __bfloat16_as_ushort(__float2bfloat16(v.x));
        u.y = __bfloat16_as_ushort(__float2bfloat16(v.y));
        u.z = __bfloat16_as_ushort(__float2bfloat16(v.z));
        u.w = __bfloat16_as_ushort(__float2bfloat16(v.w));
        *reinterpret_cast<ushort4*>(&out[(size_t)i * 4]) = u;
    }
}

// ---------------------------------------------------------------------------
// bf16 MFMA GEMM: 128x128 tile, BK=64, 4 waves x (64x64 out).
// NEW R6: T3-minimum 2-phase prefetch — double-buffered LDS, STAGE(t+1)
// issued BEFORE compute(t), one barrier per K-step (implicit vmcnt(0) drains
// a prefetch that flew under the previous compute). Compute/staging addresses
// identical to the R3/R4/R5-verified kernel.
// MODE 0: f32 out + bias. MODE 1: bf16 out + bias + exact GELU.
// MODE 2: QKV split: q (bf16, * QSCALE) / k (bf16) / vt (bf16 transposed).
// ---------------------------------------------------------------------------
#define GBM 128
#define GBN 128
#define GBK 64

template<int MODE>
__launch_bounds__(256)
__global__ void gemm_mfma(const __hip_bfloat16* __restrict__ A,
                          const __hip_bfloat16* __restrict__ Bt,
                          const float* __restrict__ bias,
                          float* __restrict__ outf,
                          __hip_bfloat16* __restrict__ outq,
                          __hip_bfloat16* __restrict__ outk,
                          __hip_bfloat16* __restrict__ outvt,
                          int M, int N, int K) {
    __shared__ __hip_bfloat16 As[2][GBM][GBK];   // 2 x 16 KB
    __shared__ __hip_bfloat16 Bs[2][GBN][GBK];   // 2 x 16 KB

    const int tid = threadIdx.x;
    const int l   = tid & 63;
    const int w   = tid >> 6;
    const int lr  = l & 15;
    const int lg  = l >> 4;
    const int wr  = w >> 1;
    const int wc  = w & 1;
    const int bm  = blockIdx.y * GBM;
    const int bn  = blockIdx.x * GBN;

    const int srow  = l >> 3;        // 0..7 row within 8-row chunk
    const int skoff = (l & 7) * 8;   // bf16 k-offset

    f32x4 acc[4][4];
    #pragma unroll
    for (int m = 0; m < 4; ++m)
        #pragma unroll
        for (int n = 0; n < 4; ++n)
            acc[m][n] = {0.f, 0.f, 0.f, 0.f};

    auto stage = [&](int buf, int k0) {
        #pragma unroll
        for (int i = 0; i < 4; ++i) {
            const int rb = (w * 4 + i) * 8;
            gload_lds16(&A[(size_t)(bm + rb + srow) * K + k0 + skoff], &As[buf][rb][0]);
            gload_lds16(&Bt[(size_t)(bn + rb + srow) * K + k0 + skoff], &Bs[buf][rb][0]);
        }
    };

    const int nk = K / GBK;
    stage(0, 0);
    for (int kt = 0; kt < nk; ++kt) {
        const int cur = kt & 1;
        __syncthreads();   // drains prefetch vmcnt; orders WAR on buf[cur^1]
        if (kt + 1 < nk) stage(cur ^ 1, (kt + 1) * GBK);

        #pragma unroll
        for (int kk = 0; kk < 2; ++kk) {
            short8 af[4], bf[4];
            #pragma unroll
            for (int m = 0; m < 4; ++m)
                af[m] = *reinterpret_cast<const short8*>(
                    &As[cur][wr * 64 + m * 16 + lr][kk * 32 + lg * 8]);
            #pragma unroll
            for (int n = 0; n < 4; ++n)
                bf[n] = *reinterpret_cast<const short8*>(
                    &Bs[cur][wc * 64 + n * 16 + lr][kk * 32 + lg * 8]);
            #pragma unroll
            for (int m = 0; m < 4; ++m)
                #pragma unroll
                for (int n = 0; n < 4; ++n)
                    acc[m][n] = __builtin_amdgcn_mfma_f32_16x16x32_bf16(af[m], bf[n], acc[m][n], 0, 0, 0);
        }
    }

    #pragma unroll
    for (int m = 0; m < 4; ++m) {
        #pragma unroll
        for (int rr = 0; rr < 4; ++rr) {
            const int row = bm + wr * 64 + m * 16 + lg * 4 + rr;
            #pragma unroll
            for (int n = 0; n < 4; ++n) {
                const int col = bn + wc * 64 + n * 16 + lr;
                float v = acc[m][n][rr] + bias[col];
                if constexpr (MODE == 0) {
                    outf[(size_t)row * N + col] = v;
                } else if constexpr (MODE == 1) {
                    v = 0.5f * v * (1.0f + erff(v * 0.70710678118654752f));
                    outq[(size_t)row * N + col] = __float2bfloat16(v);
                } else {
                    if (col < C_DIM)
                        outq[(size_t)row * C_DIM + col] = __float2bfloat16(v * QSCALE);
                    else if (col < 2 * C_DIM)
                        outk[(size_t)row * C_DIM + (col - C_DIM)] = __float2bfloat16(v);
                    else
                        outvt[(size_t)(col - 2 * C_DIM) * T_SEQ + row] = __float2bfloat16(v);
                }
            }
        }
    }
}

// ---------------------------------------------------------------------------
// Flash attention, bf16 MFMA (R5-verified: 2-phase prefetch, defer-max,
// setprio, swizzled LDS). Unchanged.
// ---------------------------------------------------------------------------
#define QBLK 64
#define KVB 128

__launch_bounds__(256)
__global__ void attn_mfma(const __hip_bfloat16* __restrict__ q,
                          const __hip_bfloat16* __restrict__ k,
                          const __hip_bfloat16* __restrict__ vt,
                          __hip_bfloat16* __restrict__ o) {
    __shared__ __hip_bfloat16 Ks[2][KVB][64];
    __shared__ __hip_bfloat16 Vts[2][D_HEAD][KVB];
    __shared__ __hip_bfloat16 Ps[4][16][KVB];

    const int tid  = threadIdx.x;
    const int wid  = tid >> 6;
    const int lane = tid & 63;
    const int lr   = lane & 15;
    const int lg   = lane >> 4;

    const int h  = blockIdx.x;
    const int q0 = T_SEQ - QBLK - blockIdx.y * QBLK;  // heavy blocks dispatch first
    const int qw = q0 + wid * 16;

    const int ksrc = 8 * ((lane & 7) ^ (lane >> 3));
    const int kr   = lane >> 3;
    const int vr   = lane >> 4;
    const int vs   = lane & 15;

    short8 aq[2];
    #pragma unroll
    for (int kk = 0; kk < 2; ++kk)
        aq[kk] = *reinterpret_cast<const short8*>(
            &q[(size_t)(qw + lr) * C_DIM + h * D_HEAD + kk * 32 + lg * 8]);

    f32x4 o_acc[4];
    #pragma unroll
    for (int dc = 0; dc < 4; ++dc) o_acc[dc] = {0.f, 0.f, 0.f, 0.f};
    float m_run[4], l_part[4];
    #pragma unroll
    for (int r = 0; r < 4; ++r) { m_run[r] = -1e30f; l_part[r] = 0.f; }

    auto stage = [&](int buf, int s0) {
        #pragma unroll
        for (int i = 0; i < 4; ++i) {
            const int rb = wid * 32 + i * 8;
            gload_lds16(&k[(size_t)(s0 + rb + kr) * C_DIM + h * D_HEAD + ksrc],
                        &Ks[buf][rb][0]);
        }
        #pragma unroll
        for (int i = 0; i < 4; ++i) {
            const int vb = wid * 16 + i * 4;
            const int vsrc = 8 * (vs ^ (i * 4 + vr));
            gload_lds16(&vt[(size_t)(h * D_HEAD + vb + vr) * T_SEQ + s0 + vsrc],
                        &Vts[buf][vb][0]);
        }
    };

    const int n_tiles = (q0 + QBLK + KVB - 1) / KVB;

    stage(0, 0);
    __syncthreads();

    for (int t = 0; t < n_tiles; ++t) {
        const int cur = t & 1;
        if (t + 1 < n_tiles) stage(cur ^ 1, (t + 1) * KVB);

        f32x4 s_acc[8];
        __builtin_amdgcn_s_setprio(1);
        #pragma unroll
        for (int c = 0; c < 8; ++c) {
            s_acc[c] = {0.f, 0.f, 0.f, 0.f};
            #pragma unroll
            for (int kk = 0; kk < 2; ++kk) {
                const short8 bk8 = *reinterpret_cast<const short8*>(
                    &Ks[cur][c * 16 + lr][8 * ((4 * kk + lg) ^ (lr & 7))]);
                s_acc[c] = __builtin_amdgcn_mfma_f32_16x16x32_bf16(aq[kk], bk8, s_acc[c], 0, 0, 0);
            }
        }
        __builtin_amdgcn_s_setprio(0);

        if (t == n_tiles - 1) {
            const int s0 = t * KVB;
            #pragma unroll
            for (int c = 0; c < 8; ++c)
                #pragma unroll
                for (int r = 0; r < 4; ++r) {
                    const int sg = s0 + c * 16 + lr;
                    const int qg = qw + lg * 4 + r;
                    if (sg > qg) s_acc[c][r] = -1e30f;
                }
        }

        float pm[4];
        #pragma unroll
        for (int r = 0; r < 4; ++r) {
            const float m0 = fmaxf(fmaxf(s_acc[0][r], s_acc[1][r]),
                                   fmaxf(s_acc[2][r], s_acc[3][r]));
            const float m1 = fmaxf(fmaxf(s_acc[4][r], s_acc[5][r]),
                                   fmaxf(s_acc[6][r], s_acc[7][r]));
            pm[r] = fmaxf(m0, m1);
        }
        const float need = fmaxf(fmaxf(pm[0] - m_run[0], pm[1] - m_run[1]),
                                 fmaxf(pm[2] - m_run[2], pm[3] - m_run[3]));
        if (!__all(need <= 8.0f)) {
            #pragma unroll
            for (int r = 0; r < 4; ++r) {
                float nm = pm[r];
                #pragma unroll
                for (int off = 1; off < 16; off <<= 1)
                    nm = fmaxf(nm, __shfl_xor(nm, off));
                nm = fmaxf(nm, m_run[r]);
                const float corr = __builtin_amdgcn_exp2f(m_run[r] - nm);
                m_run[r] = nm;
                l_part[r] *= corr;
                #pragma unroll
                for (int dc = 0; dc < 4; ++dc) o_acc[dc][r] *= corr;
            }
        }
        #pragma unroll
        for (int r = 0; r < 4; ++r) {
            const int qrow = lg * 4 + r;
            float ls = 0.f;
            #pragma unroll
            for (int c = 0; c < 8; ++c) {
                const float pv = __builtin_amdgcn_exp2f(s_acc[c][r] - m_run[r]);
                ls += pv;
                const int slot = (2 * c + (lr >> 3)) ^ qrow;
                Ps[wid][qrow][slot * 8 + (lr & 7)] = __float2bfloat16(pv);
            }
            l_part[r] += ls;
        }

        short8 ap[4];
        #pragma unroll
        for (int kk = 0; kk < 4; ++kk)
            ap[kk] = *reinterpret_cast<const short8*>(
                &Ps[wid][lr][8 * ((4 * kk + lg) ^ lr)]);
        __builtin_amdgcn_s_setprio(1);
        #pragma unroll
        for (int dc = 0; dc < 4; ++dc)
            #pragma unroll
            for (int kk = 0; kk < 4; ++kk) {
                const short8 bv8 = *reinterpret_cast<const short8*>(
                    &Vts[cur][dc * 16 + lr][8 * ((4 * kk + lg) ^ lr)]);
                o_acc[dc] = __builtin_amdgcn_mfma_f32_16x16x32_bf16(ap[kk], bv8, o_acc[dc], 0, 0, 0);
            }
        __builtin_amdgcn_s_setprio(0);

        __syncthreads();
    }

    #pragma unroll
    for (int r = 0; r < 4; ++r) {
        #pragma unroll
        for (int off = 1; off < 16; off <<= 1)
            l_part[r] += __shfl_xor(l_part[r], off);
    }

    #pragma unroll
    for (int dc = 0; dc < 4; ++dc)
        #pragma unroll
        for (int r = 0; r < 4; ++r)
            o[(size_t)(qw + lg * 4 + r) * C_DIM + h * D_HEAD + dc * 16 + lr] =
                __float2bfloat16(o_acc[dc][r] / l_part[r]);
}

// ---------------------------------------------------------------------------
// Fused residual add + LayerNorm; optional bf16 secondary output.
// ---------------------------------------------------------------------------
template<bool WB16>
__launch_bounds__(256)
__global__ void add_ln(const float* __restrict__ a, const float* __restrict__ b,
                       const float* __restrict__ g, const float* __restrict__ beta,
                       float* __restrict__ outf, __hip_bfloat16* __restrict__ outb) {
    const int row = blockIdx.x;
    const int tid = threadIdx.x;
    const size_t rb = (size_t)row * C_DIM;

    float x[3];
    #pragma unroll
    for (int i = 0; i < 3; ++i) {
        const int c = tid + 256 * i;
        x[i] = a[rb + c] + b[rb + c];
    }

    float s = x[0] + x[1] + x[2];
    float s2 = x[0] * x[0] + x[1] * x[1] + x[2] * x[2];

    #pragma unroll
    for (int off = 32; off; off >>= 1) {
        s  += __shfl_xor(s, off);
        s2 += __shfl_xor(s2, off);
    }

    __shared__ float red[10];
    const int wave = tid >> 6;
    const int lane = tid & 63;
    if (lane == 0) { red[wave] = s; red[4 + wave] = s2; }
    __syncthreads();
    if (tid == 0) {
        const float ts  = red[0] + red[1] + red[2] + red[3];
        const float ts2 = red[4] + red[5] + red[6] + red[7];
        const float mu = ts * (1.0f / C_DIM);
        const float var = ts2 * (1.0f / C_DIM) - mu * mu;
        red[8] = mu;
        red[9] = rsqrtf(var + EPS);
    }
    __syncthreads();
    const float mu = red[8];
    const float rstd = red[9];

    #pragma unroll
    for (int i = 0; i < 3; ++i) {
        const int c = tid + 256 * i;
        const float v = (x[i] - mu) * rstd * g[c] + beta[c];
        outf[rb + c] = v;
        if constexpr (WB16) outb[rb + c] = __float2bfloat16(v);
    }
}

// ---------------------------------------------------------------------------
extern "C" void kernel_launch(void* const* d_in, const int* in_sizes, int n_in,
                              void* d_out, int out_size, void* d_ws, size_t ws_size,
                              hipStream_t stream) {
    const float* x     = (const float*)d_in[0];
    const float* Wq    = (const float*)d_in[1];
    const float* bq    = (const float*)d_in[2];
    const float* Wk    = (const float*)d_in[3];
    const float* bk    = (const float*)d_in[4];
    const float* Wv    = (const float*)d_in[5];
    const float* bv    = (const float*)d_in[6];
    const float* Wo    = (const float*)d_in[7];
    const float* bo    = (const float*)d_in[8];
    const float* ln1_g = (const float*)d_in[9];
    const float* ln1_b = (const float*)d_in[10];
    const float* W1    = (const float*)d_in[11];
    const float* b1    = (const float*)d_in[12];
    const float* W2    = (const float*)d_in[13];
    const float* b2    = (const float*)d_in[14];
    const float* ln2_g = (const float*)d_in[15];
    const float* ln2_b = (const float*)d_in[16];

    float* out = (float*)d_out;

    // --- workspace arena (bytes) ---
    char* wsb = (char*)d_ws;
    const size_t TCb16 = (size_t)T_SEQ * C_DIM * 2;          // 6,291,456
    __hip_bfloat16* xb  = (__hip_bfloat16*)(wsb);
    __hip_bfloat16* qb  = (__hip_bfloat16*)(wsb + TCb16);
    __hip_bfloat16* kb  = (__hip_bfloat16*)(wsb + 2 * TCb16);
    __hip_bfloat16* vtb = (__hip_bfloat16*)(wsb + 3 * TCb16);
    __hip_bfloat16* mid = (__hip_bfloat16*)(wsb);            // [T][F] bf16 overlays A
    float* proj = (float*)(wsb + 4 * TCb16);
    float* mlpo = proj;
    __hip_bfloat16* obuf = (__hip_bfloat16*)(wsb + 4 * TCb16 + 12582912);
    __hip_bfloat16* hb   = obuf;
    float* hbuf = (float*)(wsb + 4 * TCb16 + 12582912 + TCb16);
    char* we = wsb + 4 * TCb16 + 12582912 + TCb16 + 12582912;
    __hip_bfloat16* Wqkv_t = (__hip_bfloat16*)(we);                       // [2304][768]
    __hip_bfloat16* Wo_t   = (__hip_bfloat16*)(we + 3538944);             // [768][768]
    __hip_bfloat16* W1_t   = (__hip_bfloat16*)(we + 3538944 + 1179648);   // [3072][768]
    __hip_bfloat16* W2_t   = (__hip_bfloat16*)(we + 3538944 + 1179648 + 4718592); // [768][3072]
    float* bqkv            = (float*)(we + 3538944 + 1179648 + 2 * 4718592);

    const dim3 blk256(256);

    // --- weight prep (all independent) ---
    transpose_w4<<<dim3(12, 12, 4), blk256, 0, stream>>>(Wq, Wk, Wv, Wo, Wqkv_t, Wo_t);
    transpose_w<<<dim3(12, 48), blk256, 0, stream>>>(W1, W1_t, C_DIM, F_DIM);
    transpose_w<<<dim3(48, 12), blk256, 0, stream>>>(W2, W2_t, F_DIM, C_DIM);
    concat_bias<<<dim3(3), blk256, 0, stream>>>(bq, bk, bv, bqkv);
    f32_to_bf16_vec<<<dim3(3072), blk256, 0, stream>>>(x, xb, T_SEQ * C_DIM / 4);

    // --- fused QKV GEMM: [T,768] @ [768,2304], epilogue splits q/k/vt ---
    gemm_mfma<2><<<dim3(3 * C_DIM / GBN, T_SEQ / GBM), blk256, 0, stream>>>(
        xb, Wqkv_t, bqkv, nullptr, qb, kb, vtb, T_SEQ, 3 * C_DIM, C_DIM);

    // --- flash attention (head-major grid for L2 locality) ---
    attn_mfma<<<dim3(N_HEADS, T_SEQ / QBLK), blk256, 0, stream>>>(qb, kb, vtb, obuf);

    // --- output projection -> f32 proj ---
    gemm_mfma<0><<<dim3(C_DIM / GBN, T_SEQ / GBM), blk256, 0, stream>>>(
        obuf, Wo_t, bo, proj, nullptr, nullptr, nullptr, T_SEQ, C_DIM, C_DIM);

    // --- h = LN(x + proj): f32 + bf16 ---
    add_ln<true><<<dim3(T_SEQ), blk256, 0, stream>>>(x, proj, ln1_g, ln1_b, hbuf, hb);

    // --- MLP1: gelu(h @ W1 + b1) -> bf16 mid ---
    gemm_mfma<1><<<dim3(F_DIM / GBN, T_SEQ / GBM), blk256, 0, stream>>>(
        hb, W1_t, b1, nullptr, mid, nullptr, nullptr, T_SEQ, F_DIM, C_DIM);

    // --- MLP2: mid @ W2 + b2 -> f32 mlpo ---
    gemm_mfma<0><<<dim3(C_DIM / GBN, T_SEQ / GBM), blk256, 0, stream>>>(
        mid, W2_t, b2, mlpo, nullptr, nullptr, nullptr, T_SEQ, C_DIM, F_DIM);

    // --- y = LN(h + mlpo) ---
    add_ln<false><<<dim3(T_SEQ), blk256, 0, stream>>>(hbuf, mlpo, ln2_g, ln2_b, out, nullptr);
}

// Round 7
// 336.250 us; speedup vs baseline: 1.1411x; 1.1411x over previous
//
#include <hip/hip_runtime.h>
#include <hip/hip_bf16.h>
#include <math.h>

// Problem constants
#define T_SEQ 4096
#define C_DIM 768
#define N_HEADS 12
#define D_HEAD 64
#define F_DIM 3072   // 4*C
#define EPS 1e-5f
#define QSCALE 0.18033688011112042f   // (1/8) * log2(e): softmax done in base-2

typedef __attribute__((ext_vector_type(8))) short short8;
typedef __attribute__((ext_vector_type(4))) float f32x4;

// async global->LDS, 16B per lane. LDS dest must be wave-uniform base (HW adds lane*16).
__device__ __forceinline__ void gload_lds16(const void* g, void* lds) {
    __builtin_amdgcn_global_load_lds(
        (const __attribute__((address_space(1))) unsigned int*)g,
        (__attribute__((address_space(3))) unsigned int*)lds, 16, 0, 0);
}

// ---------------------------------------------------------------------------
// Fused square-weight transpose + bf16 cast (Wq/Wk/Wv/Wo in one launch).
// ---------------------------------------------------------------------------
__launch_bounds__(256)
__global__ void transpose_w4(const float* __restrict__ Wq, const float* __restrict__ Wk,
                             const float* __restrict__ Wv, const float* __restrict__ Wo,
                             __hip_bfloat16* __restrict__ Wqkv_t,
                             __hip_bfloat16* __restrict__ Wo_t) {
    __shared__ float tile[64][65];
    const int z = blockIdx.z;
    const float* W = (z == 0) ? Wq : (z == 1) ? Wk : (z == 2) ? Wv : Wo;
    __hip_bfloat16* Wt = (z < 3) ? (Wqkv_t + (size_t)z * C_DIM * C_DIM) : Wo_t;
    const int k0 = blockIdx.x * 64;
    const int n0 = blockIdx.y * 64;
    const int tid = threadIdx.x;
    const int c = tid & 63;
    const int r0 = (tid >> 6) * 16;
    #pragma unroll
    for (int i = 0; i < 16; ++i)
        tile[r0 + i][c] = W[(size_t)(k0 + r0 + i) * C_DIM + n0 + c];
    __syncthreads();
    #pragma unroll
    for (int i = 0; i < 16; ++i)
        Wt[(size_t)(n0 + r0 + i) * C_DIM + k0 + c] = __float2bfloat16(tile[c][r0 + i]);
}

// General transpose for W1/W2.
__launch_bounds__(256)
__global__ void transpose_w(const float* __restrict__ W, __hip_bfloat16* __restrict__ Wt,
                            int K, int N) {
    __shared__ float tile[64][65];
    const int k0 = blockIdx.x * 64;
    const int n0 = blockIdx.y * 64;
    const int tid = threadIdx.x;
    const int c = tid & 63;
    const int r0 = (tid >> 6) * 16;
    #pragma unroll
    for (int i = 0; i < 16; ++i)
        tile[r0 + i][c] = W[(size_t)(k0 + r0 + i) * N + n0 + c];
    __syncthreads();
    #pragma unroll
    for (int i = 0; i < 16; ++i)
        Wt[(size_t)(n0 + r0 + i) * K + k0 + c] = __float2bfloat16(tile[c][r0 + i]);
}

// bf16 [T][C] -> bf16 [C][T] transpose (for V). Coalesced both sides via LDS.
__launch_bounds__(256)
__global__ void transpose_v(const __hip_bfloat16* __restrict__ V,
                            __hip_bfloat16* __restrict__ Vt) {
    __shared__ __hip_bfloat16 tile[64][65];   // 130B row stride -> 2-way conflicts (free)
    const int t0 = blockIdx.x * 64;
    const int c0 = blockIdx.y * 64;
    const int tid = threadIdx.x;
    const int c = tid & 63;
    const int r0 = (tid >> 6) * 16;
    #pragma unroll
    for (int i = 0; i < 16; ++i)
        tile[r0 + i][c] = V[(size_t)(t0 + r0 + i) * C_DIM + c0 + c];
    __syncthreads();
    #pragma unroll
    for (int i = 0; i < 16; ++i)
        Vt[(size_t)(c0 + r0 + i) * T_SEQ + t0 + c] = tile[c][r0 + i];
}

__launch_bounds__(256)
__global__ void concat_bias(const float* __restrict__ bq, const float* __restrict__ bk,
                            const float* __restrict__ bv, float* __restrict__ o) {
    const int i = blockIdx.x * 256 + threadIdx.x;
    if (i < C_DIM) {
        o[i] = bq[i];
        o[C_DIM + i] = bk[i];
        o[2 * C_DIM + i] = bv[i];
    }
}

__launch_bounds__(256)
__global__ void f32_to_bf16_vec(const float* __restrict__ in, __hip_bfloat16* __restrict__ out,
                                int n4) {
    const int i = blockIdx.x * 256 + threadIdx.x;
    if (i < n4) {
        const float4 v = *reinterpret_cast<const float4*>(&in[(size_t)i * 4]);
        ushort4 u;
        u.x = __bfloat16_as_ushort(__float2bfloat16(v.x));
        u.y = __bfloat16_as_ushort(__float2bfloat16(v.y));
        u.z = __bfloat16_as_ushort(__float2bfloat16(v.z));
        u.w = __bfloat16_as_ushort(__float2bfloat16(v.w));
        *reinterpret_cast<ushort4*>(&out[(size_t)i * 4]) = u;
    }
}

// ---------------------------------------------------------------------------
// bf16 MFMA GEMM, R5-verified single-buffer structure, parameterized tile.
// TM x TN tile, BK=64, 4 waves in 2x2 grid, each wave (TM/2)x(TN/2) out.
// 128x128 for big-N GEMMs (QKV, MLP1); 64x64 for N=768 GEMMs (proj, MLP2)
// to reach ~3 blocks/CU (inter-block latency hiding; m97 mechanism).
// MODE 0: f32 out + bias. MODE 1: bf16 out + bias + exact GELU.
// MODE 2: QKV split: q (bf16 * QSCALE) / k (bf16) / v (bf16, ALL row-major).
// ---------------------------------------------------------------------------
#define GBK 64

template<int MODE, int TM, int TN>
__launch_bounds__(256)
__global__ void gemm_mfma(const __hip_bfloat16* __restrict__ A,
                          const __hip_bfloat16* __restrict__ Bt,
                          const float* __restrict__ bias,
                          float* __restrict__ outf,
                          __hip_bfloat16* __restrict__ outq,
                          __hip_bfloat16* __restrict__ outk,
                          __hip_bfloat16* __restrict__ outv,
                          int M, int N, int K) {
    constexpr int WM = TM / 2, WN = TN / 2;      // per-wave output tile
    constexpr int FM = WM / 16, FN = WN / 16;    // fragment repeats
    constexpr int AISS = TM / 32, BISS = TN / 32; // 8-row staging issues per wave

    __shared__ __hip_bfloat16 As[TM][GBK];
    __shared__ __hip_bfloat16 Bs[TN][GBK];

    const int tid = threadIdx.x;
    const int l   = tid & 63;
    const int w   = tid >> 6;
    const int lr  = l & 15;
    const int lg  = l >> 4;
    const int wr  = w >> 1;
    const int wc  = w & 1;
    const int bm  = blockIdx.y * TM;
    const int bn  = blockIdx.x * TN;

    const int srow  = l >> 3;        // 0..7 row within 8-row chunk
    const int skoff = (l & 7) * 8;   // bf16 k-offset

    f32x4 acc[FM][FN];
    #pragma unroll
    for (int m = 0; m < FM; ++m)
        #pragma unroll
        for (int n = 0; n < FN; ++n)
            acc[m][n] = {0.f, 0.f, 0.f, 0.f};

    for (int k0 = 0; k0 < K; k0 += GBK) {
        if (k0) __syncthreads();
        #pragma unroll
        for (int i = 0; i < AISS; ++i) {
            const int rb = (w * AISS + i) * 8;
            gload_lds16(&A[(size_t)(bm + rb + srow) * K + k0 + skoff], &As[rb][0]);
        }
        #pragma unroll
        for (int i = 0; i < BISS; ++i) {
            const int rb = (w * BISS + i) * 8;
            gload_lds16(&Bt[(size_t)(bn + rb + srow) * K + k0 + skoff], &Bs[rb][0]);
        }
        __syncthreads();

        #pragma unroll
        for (int kk = 0; kk < 2; ++kk) {
            short8 af[FM], bf[FN];
            #pragma unroll
            for (int m = 0; m < FM; ++m)
                af[m] = *reinterpret_cast<const short8*>(
                    &As[wr * WM + m * 16 + lr][kk * 32 + lg * 8]);
            #pragma unroll
            for (int n = 0; n < FN; ++n)
                bf[n] = *reinterpret_cast<const short8*>(
                    &Bs[wc * WN + n * 16 + lr][kk * 32 + lg * 8]);
            #pragma unroll
            for (int m = 0; m < FM; ++m)
                #pragma unroll
                for (int n = 0; n < FN; ++n)
                    acc[m][n] = __builtin_amdgcn_mfma_f32_16x16x32_bf16(af[m], bf[n], acc[m][n], 0, 0, 0);
        }
    }

    #pragma unroll
    for (int m = 0; m < FM; ++m) {
        #pragma unroll
        for (int rr = 0; rr < 4; ++rr) {
            const int row = bm + wr * WM + m * 16 + lg * 4 + rr;
            #pragma unroll
            for (int n = 0; n < FN; ++n) {
                const int col = bn + wc * WN + n * 16 + lr;
                float v = acc[m][n][rr] + bias[col];
                if constexpr (MODE == 0) {
                    outf[(size_t)row * N + col] = v;
                } else if constexpr (MODE == 1) {
                    v = 0.5f * v * (1.0f + erff(v * 0.70710678118654752f));
                    outq[(size_t)row * N + col] = __float2bfloat16(v);
                } else {
                    if (col < C_DIM)
                        outq[(size_t)row * C_DIM + col] = __float2bfloat16(v * QSCALE);
                    else if (col < 2 * C_DIM)
                        outk[(size_t)row * C_DIM + (col - C_DIM)] = __float2bfloat16(v);
                    else
                        outv[(size_t)row * C_DIM + (col - 2 * C_DIM)] = __float2bfloat16(v);
                }
            }
        }
    }
}

// ---------------------------------------------------------------------------
// Flash attention, bf16 MFMA (R5-verified: 2-phase prefetch, defer-max,
// setprio, swizzled LDS). Unchanged.
// ---------------------------------------------------------------------------
#define QBLK 64
#define KVB 128

__launch_bounds__(256)
__global__ void attn_mfma(const __hip_bfloat16* __restrict__ q,
                          const __hip_bfloat16* __restrict__ k,
                          const __hip_bfloat16* __restrict__ vt,
                          __hip_bfloat16* __restrict__ o) {
    __shared__ __hip_bfloat16 Ks[2][KVB][64];
    __shared__ __hip_bfloat16 Vts[2][D_HEAD][KVB];
    __shared__ __hip_bfloat16 Ps[4][16][KVB];

    const int tid  = threadIdx.x;
    const int wid  = tid >> 6;
    const int lane = tid & 63;
    const int lr   = lane & 15;
    const int lg   = lane >> 4;

    const int h  = blockIdx.x;
    const int q0 = T_SEQ - QBLK - blockIdx.y * QBLK;  // heavy blocks dispatch first
    const int qw = q0 + wid * 16;

    const int ksrc = 8 * ((lane & 7) ^ (lane >> 3));
    const int kr   = lane >> 3;
    const int vr   = lane >> 4;
    const int vs   = lane & 15;

    short8 aq[2];
    #pragma unroll
    for (int kk = 0; kk < 2; ++kk)
        aq[kk] = *reinterpret_cast<const short8*>(
            &q[(size_t)(qw + lr) * C_DIM + h * D_HEAD + kk * 32 + lg * 8]);

    f32x4 o_acc[4];
    #pragma unroll
    for (int dc = 0; dc < 4; ++dc) o_acc[dc] = {0.f, 0.f, 0.f, 0.f};
    float m_run[4], l_part[4];
    #pragma unroll
    for (int r = 0; r < 4; ++r) { m_run[r] = -1e30f; l_part[r] = 0.f; }

    auto stage = [&](int buf, int s0) {
        #pragma unroll
        for (int i = 0; i < 4; ++i) {
            const int rb = wid * 32 + i * 8;
            gload_lds16(&k[(size_t)(s0 + rb + kr) * C_DIM + h * D_HEAD + ksrc],
                        &Ks[buf][rb][0]);
        }
        #pragma unroll
        for (int i = 0; i < 4; ++i) {
            const int vb = wid * 16 + i * 4;
            const int vsrc = 8 * (vs ^ (i * 4 + vr));
            gload_lds16(&vt[(size_t)(h * D_HEAD + vb + vr) * T_SEQ + s0 + vsrc],
                        &Vts[buf][vb][0]);
        }
    };

    const int n_tiles = (q0 + QBLK + KVB - 1) / KVB;

    stage(0, 0);
    __syncthreads();

    for (int t = 0; t < n_tiles; ++t) {
        const int cur = t & 1;
        if (t + 1 < n_tiles) stage(cur ^ 1, (t + 1) * KVB);

        f32x4 s_acc[8];
        __builtin_amdgcn_s_setprio(1);
        #pragma unroll
        for (int c = 0; c < 8; ++c) {
            s_acc[c] = {0.f, 0.f, 0.f, 0.f};
            #pragma unroll
            for (int kk = 0; kk < 2; ++kk) {
                const short8 bk8 = *reinterpret_cast<const short8*>(
                    &Ks[cur][c * 16 + lr][8 * ((4 * kk + lg) ^ (lr & 7))]);
                s_acc[c] = __builtin_amdgcn_mfma_f32_16x16x32_bf16(aq[kk], bk8, s_acc[c], 0, 0, 0);
            }
        }
        __builtin_amdgcn_s_setprio(0);

        if (t == n_tiles - 1) {
            const int s0 = t * KVB;
            #pragma unroll
            for (int c = 0; c < 8; ++c)
                #pragma unroll
                for (int r = 0; r < 4; ++r) {
                    const int sg = s0 + c * 16 + lr;
                    const int qg = qw + lg * 4 + r;
                    if (sg > qg) s_acc[c][r] = -1e30f;
                }
        }

        float pm[4];
        #pragma unroll
        for (int r = 0; r < 4; ++r) {
            const float m0 = fmaxf(fmaxf(s_acc[0][r], s_acc[1][r]),
                                   fmaxf(s_acc[2][r], s_acc[3][r]));
            const float m1 = fmaxf(fmaxf(s_acc[4][r], s_acc[5][r]),
                                   fmaxf(s_acc[6][r], s_acc[7][r]));
            pm[r] = fmaxf(m0, m1);
        }
        const float need = fmaxf(fmaxf(pm[0] - m_run[0], pm[1] - m_run[1]),
                                 fmaxf(pm[2] - m_run[2], pm[3] - m_run[3]));
        if (!__all(need <= 8.0f)) {
            #pragma unroll
            for (int r = 0; r < 4; ++r) {
                float nm = pm[r];
                #pragma unroll
                for (int off = 1; off < 16; off <<= 1)
                    nm = fmaxf(nm, __shfl_xor(nm, off));
                nm = fmaxf(nm, m_run[r]);
                const float corr = __builtin_amdgcn_exp2f(m_run[r] - nm);
                m_run[r] = nm;
                l_part[r] *= corr;
                #pragma unroll
                for (int dc = 0; dc < 4; ++dc) o_acc[dc][r] *= corr;
            }
        }
        #pragma unroll
        for (int r = 0; r < 4; ++r) {
            const int qrow = lg * 4 + r;
            float ls = 0.f;
            #pragma unroll
            for (int c = 0; c < 8; ++c) {
                const float pv = __builtin_amdgcn_exp2f(s_acc[c][r] - m_run[r]);
                ls += pv;
                const int slot = (2 * c + (lr >> 3)) ^ qrow;
                Ps[wid][qrow][slot * 8 + (lr & 7)] = __float2bfloat16(pv);
            }
            l_part[r] += ls;
        }

        short8 ap[4];
        #pragma unroll
        for (int kk = 0; kk < 4; ++kk)
            ap[kk] = *reinterpret_cast<const short8*>(
                &Ps[wid][lr][8 * ((4 * kk + lg) ^ lr)]);
        __builtin_amdgcn_s_setprio(1);
        #pragma unroll
        for (int dc = 0; dc < 4; ++dc)
            #pragma unroll
            for (int kk = 0; kk < 4; ++kk) {
                const short8 bv8 = *reinterpret_cast<const short8*>(
                    &Vts[cur][dc * 16 + lr][8 * ((4 * kk + lg) ^ lr)]);
                o_acc[dc] = __builtin_amdgcn_mfma_f32_16x16x32_bf16(ap[kk], bv8, o_acc[dc], 0, 0, 0);
            }
        __builtin_amdgcn_s_setprio(0);

        __syncthreads();
    }

    #pragma unroll
    for (int r = 0; r < 4; ++r) {
        #pragma unroll
        for (int off = 1; off < 16; off <<= 1)
            l_part[r] += __shfl_xor(l_part[r], off);
    }

    #pragma unroll
    for (int dc = 0; dc < 4; ++dc)
        #pragma unroll
        for (int r = 0; r < 4; ++r)
            o[(size_t)(qw + lg * 4 + r) * C_DIM + h * D_HEAD + dc * 16 + lr] =
                __float2bfloat16(o_acc[dc][r] / l_part[r]);
}

// ---------------------------------------------------------------------------
// Fused residual add + LayerNorm; optional bf16 secondary output.
// ---------------------------------------------------------------------------
template<bool WB16>
__launch_bounds__(256)
__global__ void add_ln(const float* __restrict__ a, const float* __restrict__ b,
                       const float* __restrict__ g, const float* __restrict__ beta,
                       float* __restrict__ outf, __hip_bfloat16* __restrict__ outb) {
    const int row = blockIdx.x;
    const int tid = threadIdx.x;
    const size_t rb = (size_t)row * C_DIM;

    float x[3];
    #pragma unroll
    for (int i = 0; i < 3; ++i) {
        const int c = tid + 256 * i;
        x[i] = a[rb + c] + b[rb + c];
    }

    float s = x[0] + x[1] + x[2];
    float s2 = x[0] * x[0] + x[1] * x[1] + x[2] * x[2];

    #pragma unroll
    for (int off = 32; off; off >>= 1) {
        s  += __shfl_xor(s, off);
        s2 += __shfl_xor(s2, off);
    }

    __shared__ float red[10];
    const int wave = tid >> 6;
    const int lane = tid & 63;
    if (lane == 0) { red[wave] = s; red[4 + wave] = s2; }
    __syncthreads();
    if (tid == 0) {
        const float ts  = red[0] + red[1] + red[2] + red[3];
        const float ts2 = red[4] + red[5] + red[6] + red[7];
        const float mu = ts * (1.0f / C_DIM);
        const float var = ts2 * (1.0f / C_DIM) - mu * mu;
        red[8] = mu;
        red[9] = rsqrtf(var + EPS);
    }
    __syncthreads();
    const float mu = red[8];
    const float rstd = red[9];

    #pragma unroll
    for (int i = 0; i < 3; ++i) {
        const int c = tid + 256 * i;
        const float v = (x[i] - mu) * rstd * g[c] + beta[c];
        outf[rb + c] = v;
        if constexpr (WB16) outb[rb + c] = __float2bfloat16(v);
    }
}

// ---------------------------------------------------------------------------
extern "C" void kernel_launch(void* const* d_in, const int* in_sizes, int n_in,
                              void* d_out, int out_size, void* d_ws, size_t ws_size,
                              hipStream_t stream) {
    const float* x     = (const float*)d_in[0];
    const float* Wq    = (const float*)d_in[1];
    const float* bq    = (const float*)d_in[2];
    const float* Wk    = (const float*)d_in[3];
    const float* bk    = (const float*)d_in[4];
    const float* Wv    = (const float*)d_in[5];
    const float* bv    = (const float*)d_in[6];
    const float* Wo    = (const float*)d_in[7];
    const float* bo    = (const float*)d_in[8];
    const float* ln1_g = (const float*)d_in[9];
    const float* ln1_b = (const float*)d_in[10];
    const float* W1    = (const float*)d_in[11];
    const float* b1    = (const float*)d_in[12];
    const float* W2    = (const float*)d_in[13];
    const float* b2    = (const float*)d_in[14];
    const float* ln2_g = (const float*)d_in[15];
    const float* ln2_b = (const float*)d_in[16];

    float* out = (float*)d_out;

    // --- workspace arena (bytes) ---
    char* wsb = (char*)d_ws;
    const size_t TCb16 = (size_t)T_SEQ * C_DIM * 2;          // 6,291,456
    __hip_bfloat16* xb  = (__hip_bfloat16*)(wsb);
    __hip_bfloat16* qb  = (__hip_bfloat16*)(wsb + TCb16);
    __hip_bfloat16* kb  = (__hip_bfloat16*)(wsb + 2 * TCb16);
    __hip_bfloat16* vtb = (__hip_bfloat16*)(wsb + 3 * TCb16);
    __hip_bfloat16* mid = (__hip_bfloat16*)(wsb);            // [T][F] bf16 overlays A region
    float* proj = (float*)(wsb + 4 * TCb16);                 // f32 [T][C]
    __hip_bfloat16* vb = (__hip_bfloat16*)proj;              // V row-major (dead before proj write)
    float* mlpo = proj;
    __hip_bfloat16* obuf = (__hip_bfloat16*)(wsb + 4 * TCb16 + 12582912);
    __hip_bfloat16* hb   = obuf;
    float* hbuf = (float*)(wsb + 4 * TCb16 + 12582912 + TCb16);
    char* we = wsb + 4 * TCb16 + 12582912 + TCb16 + 12582912;
    __hip_bfloat16* Wqkv_t = (__hip_bfloat16*)(we);                       // [2304][768]
    __hip_bfloat16* Wo_t   = (__hip_bfloat16*)(we + 3538944);             // [768][768]
    __hip_bfloat16* W1_t   = (__hip_bfloat16*)(we + 3538944 + 1179648);   // [3072][768]
    __hip_bfloat16* W2_t   = (__hip_bfloat16*)(we + 3538944 + 1179648 + 4718592); // [768][3072]
    float* bqkv            = (float*)(we + 3538944 + 1179648 + 2 * 4718592);

    const dim3 blk256(256);

    // --- weight prep (all independent) ---
    transpose_w4<<<dim3(12, 12, 4), blk256, 0, stream>>>(Wq, Wk, Wv, Wo, Wqkv_t, Wo_t);
    transpose_w<<<dim3(12, 48), blk256, 0, stream>>>(W1, W1_t, C_DIM, F_DIM);
    transpose_w<<<dim3(48, 12), blk256, 0, stream>>>(W2, W2_t, F_DIM, C_DIM);
    concat_bias<<<dim3(3), blk256, 0, stream>>>(bq, bk, bv, bqkv);
    f32_to_bf16_vec<<<dim3(3072), blk256, 0, stream>>>(x, xb, T_SEQ * C_DIM / 4);

    // --- fused QKV GEMM: [T,768] @ [768,2304]; q/k/v all row-major out ---
    gemm_mfma<2, 128, 128><<<dim3(3 * C_DIM / 128, T_SEQ / 128), blk256, 0, stream>>>(
        xb, Wqkv_t, bqkv, nullptr, qb, kb, vb, T_SEQ, 3 * C_DIM, C_DIM);

    // --- V transpose (coalesced LDS-tiled): vb [T][C] -> vtb [C][T] ---
    transpose_v<<<dim3(T_SEQ / 64, C_DIM / 64), blk256, 0, stream>>>(vb, vtb);

    // --- flash attention (head-major grid for L2 locality) ---
    attn_mfma<<<dim3(N_HEADS, T_SEQ / QBLK), blk256, 0, stream>>>(qb, kb, vtb, obuf);

    // --- output projection -> f32 proj (64x64 tiles: 768 blocks, ~3/CU) ---
    gemm_mfma<0, 64, 64><<<dim3(C_DIM / 64, T_SEQ / 64), blk256, 0, stream>>>(
        obuf, Wo_t, bo, proj, nullptr, nullptr, nullptr, T_SEQ, C_DIM, C_DIM);

    // --- h = LN(x + proj): f32 + bf16 ---
    add_ln<true><<<dim3(T_SEQ), blk256, 0, stream>>>(x, proj, ln1_g, ln1_b, hbuf, hb);

    // --- MLP1: gelu(h @ W1 + b1) -> bf16 mid ---
    gemm_mfma<1, 128, 128><<<dim3(F_DIM / 128, T_SEQ / 128), blk256, 0, stream>>>(
        hb, W1_t, b1, nullptr, mid, nullptr, nullptr, T_SEQ, F_DIM, C_DIM);

    // --- MLP2: mid @ W2 + b2 -> f32 mlpo (64x64 tiles) ---
    gemm_mfma<0, 64, 64><<<dim3(C_DIM / 64, T_SEQ / 64), blk256, 0, stream>>>(
        mid, W2_t, b2, mlpo, nullptr, nullptr, nullptr, T_SEQ, C_DIM, F_DIM);

    // --- y = LN(h + mlpo) ---
    add_ln<false><<<dim3(T_SEQ), blk256, 0, stream>>>(hbuf, mlpo, ln2_g, ln2_b, out, nullptr);
}

// Round 8
// 318.594 us; speedup vs baseline: 1.2043x; 1.0554x over previous
//
#include <hip/hip_runtime.h>
#include <hip/hip_bf16.h>
#include <math.h>

// Problem constants
#define T_SEQ 4096
#define C_DIM 768
#define N_HEADS 12
#define D_HEAD 64
#define F_DIM 3072   // 4*C
#define EPS 1e-5f
#define QSCALE 0.18033688011112042f   // (1/8) * log2(e): softmax done in base-2

typedef __attribute__((ext_vector_type(8))) short short8;
typedef __attribute__((ext_vector_type(4))) float f32x4;

// async global->LDS, 16B per lane. LDS dest must be wave-uniform base (HW adds lane*16).
__device__ __forceinline__ void gload_lds16(const void* g, void* lds) {
    __builtin_amdgcn_global_load_lds(
        (const __attribute__((address_space(1))) unsigned int*)g,
        (__attribute__((address_space(3))) unsigned int*)lds, 16, 0, 0);
}

// ---------------------------------------------------------------------------
// ONE prep kernel (graph stream is serial: fewer launches = less dead time).
// blocks [0,1728): 64x64 weight-transpose tiles (Wq,Wk,Wv,Wo,W1,W2 -> bf16 Wt)
// blocks [1728,4800): x f32 -> bf16 (4 elems/thread)
// blocks [4800,4803): bias concat
// ---------------------------------------------------------------------------
__launch_bounds__(256)
__global__ void prep_all(const float* __restrict__ Wq, const float* __restrict__ Wk,
                         const float* __restrict__ Wv, const float* __restrict__ Wo,
                         const float* __restrict__ W1, const float* __restrict__ W2,
                         const float* __restrict__ x,
                         const float* __restrict__ bq, const float* __restrict__ bk,
                         const float* __restrict__ bv,
                         __hip_bfloat16* __restrict__ Wqkv_t, __hip_bfloat16* __restrict__ Wo_t,
                         __hip_bfloat16* __restrict__ W1_t, __hip_bfloat16* __restrict__ W2_t,
                         __hip_bfloat16* __restrict__ xb, float* __restrict__ bqkv) {
    const int b = blockIdx.x;
    const int tid = threadIdx.x;
    if (b < 1728) {
        __shared__ float tile[64][65];
        const float* W; __hip_bfloat16* Wt; int K, N, kx, ny;
        if (b < 576) {
            const int z = b / 144, t = b % 144;
            kx = t % 12; ny = t / 12; K = C_DIM; N = C_DIM;
            W  = (z == 0) ? Wq : (z == 1) ? Wk : (z == 2) ? Wv : Wo;
            Wt = (z < 3) ? (Wqkv_t + (size_t)z * C_DIM * C_DIM) : Wo_t;
        } else if (b < 1152) {
            const int t = b - 576; kx = t % 12; ny = t / 12;
            K = C_DIM; N = F_DIM; W = W1; Wt = W1_t;
        } else {
            const int t = b - 1152; kx = t % 48; ny = t / 48;
            K = F_DIM; N = C_DIM; W = W2; Wt = W2_t;
        }
        const int k0 = kx * 64, n0 = ny * 64;
        const int c = tid & 63, r0 = (tid >> 6) * 16;
        #pragma unroll
        for (int i = 0; i < 16; ++i)
            tile[r0 + i][c] = W[(size_t)(k0 + r0 + i) * N + n0 + c];
        __syncthreads();
        #pragma unroll
        for (int i = 0; i < 16; ++i)
            Wt[(size_t)(n0 + r0 + i) * K + k0 + c] = __float2bfloat16(tile[c][r0 + i]);
    } else if (b < 4800) {
        const int i = (b - 1728) * 256 + tid;   // < 786432 = T*C/4
        const float4 v = *reinterpret_cast<const float4*>(&x[(size_t)i * 4]);
        ushort4 u;
        u.x = __bfloat16_as_ushort(__float2bfloat16(v.x));
        u.y = __bfloat16_as_ushort(__float2bfloat16(v.y));
        u.z = __bfloat16_as_ushort(__float2bfloat16(v.z));
        u.w = __bfloat16_as_ushort(__float2bfloat16(v.w));
        *reinterpret_cast<ushort4*>(&xb[(size_t)i * 4]) = u;
    } else {
        const int i = (b - 4800) * 256 + tid;
        if (i < C_DIM) {
            bqkv[i] = bq[i];
            bqkv[C_DIM + i] = bk[i];
            bqkv[2 * C_DIM + i] = bv[i];
        }
    }
}

// bf16 [T][C] -> bf16 [C][T] transpose (for V). Coalesced both sides via LDS.
__launch_bounds__(256)
__global__ void transpose_v(const __hip_bfloat16* __restrict__ V,
                            __hip_bfloat16* __restrict__ Vt) {
    __shared__ __hip_bfloat16 tile[64][65];
    const int t0 = blockIdx.x * 64;
    const int c0 = blockIdx.y * 64;
    const int tid = threadIdx.x;
    const int c = tid & 63;
    const int r0 = (tid >> 6) * 16;
    #pragma unroll
    for (int i = 0; i < 16; ++i)
        tile[r0 + i][c] = V[(size_t)(t0 + r0 + i) * C_DIM + c0 + c];
    __syncthreads();
    #pragma unroll
    for (int i = 0; i < 16; ++i)
        Vt[(size_t)(c0 + r0 + i) * T_SEQ + t0 + c] = tile[c][r0 + i];
}

// ---------------------------------------------------------------------------
// bf16 MFMA GEMM, R5/R7-verified single-buffer structure, parameterized:
// TM x TN tile, BK=64, 4 waves (2x2), wave = (TM/2)x(TN/2) out.
// SPLITK: blockIdx.z splits K; slice z writes outf + z*M*N (f32 partials,
//         bias only in z==0). Halves the serial stage-drain chain and
//         doubles resident blocks for the N=768 shapes.
// SWZ: XCD-aware bijective block remap (requires nwg%8==0) - T1.
// MODE 0: f32 out + bias. MODE 1: bf16 out + bias + exact GELU.
// MODE 2: QKV split: q (bf16 * QSCALE) / k (bf16) / v (bf16, row-major).
// ---------------------------------------------------------------------------
#define GBK 64

template<int MODE, int TM, int TN, int SPLITK, bool SWZ>
__launch_bounds__(256)
__global__ void gemm_mfma(const __hip_bfloat16* __restrict__ A,
                          const __hip_bfloat16* __restrict__ Bt,
                          const float* __restrict__ bias,
                          float* __restrict__ outf,
                          __hip_bfloat16* __restrict__ outq,
                          __hip_bfloat16* __restrict__ outk,
                          __hip_bfloat16* __restrict__ outv,
                          int M, int N, int K) {
    constexpr int WM = TM / 2, WN = TN / 2;
    constexpr int FM = WM / 16, FN = WN / 16;
    constexpr int AISS = TM / 32, BISS = TN / 32;

    __shared__ __hip_bfloat16 As[TM][GBK];
    __shared__ __hip_bfloat16 Bs[TN][GBK];

    const int tid = threadIdx.x;
    const int l   = tid & 63;
    const int w   = tid >> 6;
    const int lr  = l & 15;
    const int lg  = l >> 4;
    const int wr  = w >> 1;
    const int wc  = w & 1;

    int bid = blockIdx.y * gridDim.x + blockIdx.x;
    if constexpr (SWZ) {
        const int nwg = gridDim.x * gridDim.y;   // must be %8==0 (it is: 576/768)
        const int cpx = nwg >> 3;
        bid = (bid & 7) * cpx + (bid >> 3);
    }
    const int bm = (bid / gridDim.x) * TM;
    const int bn = (bid % gridDim.x) * TN;

    const int kz   = (SPLITK > 1) ? blockIdx.z : 0;
    const int kbeg = kz * (K / SPLITK);
    const int kend = kbeg + K / SPLITK;

    const int srow  = l >> 3;
    const int skoff = (l & 7) * 8;

    f32x4 acc[FM][FN];
    #pragma unroll
    for (int m = 0; m < FM; ++m)
        #pragma unroll
        for (int n = 0; n < FN; ++n)
            acc[m][n] = {0.f, 0.f, 0.f, 0.f};

    for (int k0 = kbeg; k0 < kend; k0 += GBK) {
        if (k0 != kbeg) __syncthreads();
        #pragma unroll
        for (int i = 0; i < AISS; ++i) {
            const int rb = (w * AISS + i) * 8;
            gload_lds16(&A[(size_t)(bm + rb + srow) * K + k0 + skoff], &As[rb][0]);
        }
        #pragma unroll
        for (int i = 0; i < BISS; ++i) {
            const int rb = (w * BISS + i) * 8;
            gload_lds16(&Bt[(size_t)(bn + rb + srow) * K + k0 + skoff], &Bs[rb][0]);
        }
        __syncthreads();

        #pragma unroll
        for (int kk = 0; kk < 2; ++kk) {
            short8 af[FM], bf[FN];
            #pragma unroll
            for (int m = 0; m < FM; ++m)
                af[m] = *reinterpret_cast<const short8*>(
                    &As[wr * WM + m * 16 + lr][kk * 32 + lg * 8]);
            #pragma unroll
            for (int n = 0; n < FN; ++n)
                bf[n] = *reinterpret_cast<const short8*>(
                    &Bs[wc * WN + n * 16 + lr][kk * 32 + lg * 8]);
            #pragma unroll
            for (int m = 0; m < FM; ++m)
                #pragma unroll
                for (int n = 0; n < FN; ++n)
                    acc[m][n] = __builtin_amdgcn_mfma_f32_16x16x32_bf16(af[m], bf[n], acc[m][n], 0, 0, 0);
        }
    }

    #pragma unroll
    for (int m = 0; m < FM; ++m) {
        #pragma unroll
        for (int rr = 0; rr < 4; ++rr) {
            const int row = bm + wr * WM + m * 16 + lg * 4 + rr;
            #pragma unroll
            for (int n = 0; n < FN; ++n) {
                const int col = bn + wc * WN + n * 16 + lr;
                float v = acc[m][n][rr] + ((SPLITK == 1 || kz == 0) ? bias[col] : 0.f);
                if constexpr (MODE == 0) {
                    outf[(size_t)kz * M * N + (size_t)row * N + col] = v;
                } else if constexpr (MODE == 1) {
                    v = 0.5f * v * (1.0f + erff(v * 0.70710678118654752f));
                    outq[(size_t)row * N + col] = __float2bfloat16(v);
                } else {
                    if (col < C_DIM)
                        outq[(size_t)row * C_DIM + col] = __float2bfloat16(v * QSCALE);
                    else if (col < 2 * C_DIM)
                        outk[(size_t)row * C_DIM + (col - C_DIM)] = __float2bfloat16(v);
                    else
                        outv[(size_t)row * C_DIM + (col - 2 * C_DIM)] = __float2bfloat16(v);
                }
            }
        }
    }
}

// ---------------------------------------------------------------------------
// Flash attention, bf16 MFMA (R5-verified: 2-phase prefetch, defer-max,
// setprio, swizzled LDS). Unchanged.
// ---------------------------------------------------------------------------
#define QBLK 64
#define KVB 128

__launch_bounds__(256)
__global__ void attn_mfma(const __hip_bfloat16* __restrict__ q,
                          const __hip_bfloat16* __restrict__ k,
                          const __hip_bfloat16* __restrict__ vt,
                          __hip_bfloat16* __restrict__ o) {
    __shared__ __hip_bfloat16 Ks[2][KVB][64];
    __shared__ __hip_bfloat16 Vts[2][D_HEAD][KVB];
    __shared__ __hip_bfloat16 Ps[4][16][KVB];

    const int tid  = threadIdx.x;
    const int wid  = tid >> 6;
    const int lane = tid & 63;
    const int lr   = lane & 15;
    const int lg   = lane >> 4;

    const int h  = blockIdx.x;
    const int q0 = T_SEQ - QBLK - blockIdx.y * QBLK;
    const int qw = q0 + wid * 16;

    const int ksrc = 8 * ((lane & 7) ^ (lane >> 3));
    const int kr   = lane >> 3;
    const int vr   = lane >> 4;
    const int vs   = lane & 15;

    short8 aq[2];
    #pragma unroll
    for (int kk = 0; kk < 2; ++kk)
        aq[kk] = *reinterpret_cast<const short8*>(
            &q[(size_t)(qw + lr) * C_DIM + h * D_HEAD + kk * 32 + lg * 8]);

    f32x4 o_acc[4];
    #pragma unroll
    for (int dc = 0; dc < 4; ++dc) o_acc[dc] = {0.f, 0.f, 0.f, 0.f};
    float m_run[4], l_part[4];
    #pragma unroll
    for (int r = 0; r < 4; ++r) { m_run[r] = -1e30f; l_part[r] = 0.f; }

    auto stage = [&](int buf, int s0) {
        #pragma unroll
        for (int i = 0; i < 4; ++i) {
            const int rb = wid * 32 + i * 8;
            gload_lds16(&k[(size_t)(s0 + rb + kr) * C_DIM + h * D_HEAD + ksrc],
                        &Ks[buf][rb][0]);
        }
        #pragma unroll
        for (int i = 0; i < 4; ++i) {
            const int vb = wid * 16 + i * 4;
            const int vsrc = 8 * (vs ^ (i * 4 + vr));
            gload_lds16(&vt[(size_t)(h * D_HEAD + vb + vr) * T_SEQ + s0 + vsrc],
                        &Vts[buf][vb][0]);
        }
    };

    const int n_tiles = (q0 + QBLK + KVB - 1) / KVB;

    stage(0, 0);
    __syncthreads();

    for (int t = 0; t < n_tiles; ++t) {
        const int cur = t & 1;
        if (t + 1 < n_tiles) stage(cur ^ 1, (t + 1) * KVB);

        f32x4 s_acc[8];
        __builtin_amdgcn_s_setprio(1);
        #pragma unroll
        for (int c = 0; c < 8; ++c) {
            s_acc[c] = {0.f, 0.f, 0.f, 0.f};
            #pragma unroll
            for (int kk = 0; kk < 2; ++kk) {
                const short8 bk8 = *reinterpret_cast<const short8*>(
                    &Ks[cur][c * 16 + lr][8 * ((4 * kk + lg) ^ (lr & 7))]);
                s_acc[c] = __builtin_amdgcn_mfma_f32_16x16x32_bf16(aq[kk], bk8, s_acc[c], 0, 0, 0);
            }
        }
        __builtin_amdgcn_s_setprio(0);

        if (t == n_tiles - 1) {
            const int s0 = t * KVB;
            #pragma unroll
            for (int c = 0; c < 8; ++c)
                #pragma unroll
                for (int r = 0; r < 4; ++r) {
                    const int sg = s0 + c * 16 + lr;
                    const int qg = qw + lg * 4 + r;
                    if (sg > qg) s_acc[c][r] = -1e30f;
                }
        }

        float pm[4];
        #pragma unroll
        for (int r = 0; r < 4; ++r) {
            const float m0 = fmaxf(fmaxf(s_acc[0][r], s_acc[1][r]),
                                   fmaxf(s_acc[2][r], s_acc[3][r]));
            const float m1 = fmaxf(fmaxf(s_acc[4][r], s_acc[5][r]),
                                   fmaxf(s_acc[6][r], s_acc[7][r]));
            pm[r] = fmaxf(m0, m1);
        }
        const float need = fmaxf(fmaxf(pm[0] - m_run[0], pm[1] - m_run[1]),
                                 fmaxf(pm[2] - m_run[2], pm[3] - m_run[3]));
        if (!__all(need <= 8.0f)) {
            #pragma unroll
            for (int r = 0; r < 4; ++r) {
                float nm = pm[r];
                #pragma unroll
                for (int off = 1; off < 16; off <<= 1)
                    nm = fmaxf(nm, __shfl_xor(nm, off));
                nm = fmaxf(nm, m_run[r]);
                const float corr = __builtin_amdgcn_exp2f(m_run[r] - nm);
                m_run[r] = nm;
                l_part[r] *= corr;
                #pragma unroll
                for (int dc = 0; dc < 4; ++dc) o_acc[dc][r] *= corr;
            }
        }
        #pragma unroll
        for (int r = 0; r < 4; ++r) {
            const int qrow = lg * 4 + r;
            float ls = 0.f;
            #pragma unroll
            for (int c = 0; c < 8; ++c) {
                const float pv = __builtin_amdgcn_exp2f(s_acc[c][r] - m_run[r]);
                ls += pv;
                const int slot = (2 * c + (lr >> 3)) ^ qrow;
                Ps[wid][qrow][slot * 8 + (lr & 7)] = __float2bfloat16(pv);
            }
            l_part[r] += ls;
        }

        short8 ap[4];
        #pragma unroll
        for (int kk = 0; kk < 4; ++kk)
            ap[kk] = *reinterpret_cast<const short8*>(
                &Ps[wid][lr][8 * ((4 * kk + lg) ^ lr)]);
        __builtin_amdgcn_s_setprio(1);
        #pragma unroll
        for (int dc = 0; dc < 4; ++dc)
            #pragma unroll
            for (int kk = 0; kk < 4; ++kk) {
                const short8 bv8 = *reinterpret_cast<const short8*>(
                    &Vts[cur][dc * 16 + lr][8 * ((4 * kk + lg) ^ lr)]);
                o_acc[dc] = __builtin_amdgcn_mfma_f32_16x16x32_bf16(ap[kk], bv8, o_acc[dc], 0, 0, 0);
            }
        __builtin_amdgcn_s_setprio(0);

        __syncthreads();
    }

    #pragma unroll
    for (int r = 0; r < 4; ++r) {
        #pragma unroll
        for (int off = 1; off < 16; off <<= 1)
            l_part[r] += __shfl_xor(l_part[r], off);
    }

    #pragma unroll
    for (int dc = 0; dc < 4; ++dc)
        #pragma unroll
        for (int r = 0; r < 4; ++r)
            o[(size_t)(qw + lg * 4 + r) * C_DIM + h * D_HEAD + dc * 16 + lr] =
                __float2bfloat16(o_acc[dc][r] / l_part[r]);
}

// ---------------------------------------------------------------------------
// Fused (a + b0 + b1) + LayerNorm; optional bf16 secondary output.
// b1 is the second split-K partial.
// ---------------------------------------------------------------------------
template<bool WB16>
__launch_bounds__(256)
__global__ void add_ln(const float* __restrict__ a, const float* __restrict__ b0,
                       const float* __restrict__ b1,
                       const float* __restrict__ g, const float* __restrict__ beta,
                       float* __restrict__ outf, __hip_bfloat16* __restrict__ outb) {
    const int row = blockIdx.x;
    const int tid = threadIdx.x;
    const size_t rb = (size_t)row * C_DIM;

    float x[3];
    #pragma unroll
    for (int i = 0; i < 3; ++i) {
        const int c = tid + 256 * i;
        x[i] = a[rb + c] + b0[rb + c] + b1[rb + c];
    }

    float s = x[0] + x[1] + x[2];
    float s2 = x[0] * x[0] + x[1] * x[1] + x[2] * x[2];

    #pragma unroll
    for (int off = 32; off; off >>= 1) {
        s  += __shfl_xor(s, off);
        s2 += __shfl_xor(s2, off);
    }

    __shared__ float red[10];
    const int wave = tid >> 6;
    const int lane = tid & 63;
    if (lane == 0) { red[wave] = s; red[4 + wave] = s2; }
    __syncthreads();
    if (tid == 0) {
        const float ts  = red[0] + red[1] + red[2] + red[3];
        const float ts2 = red[4] + red[5] + red[6] + red[7];
        const float mu = ts * (1.0f / C_DIM);
        const float var = ts2 * (1.0f / C_DIM) - mu * mu;
        red[8] = mu;
        red[9] = rsqrtf(var + EPS);
    }
    __syncthreads();
    const float mu = red[8];
    const float rstd = red[9];

    #pragma unroll
    for (int i = 0; i < 3; ++i) {
        const int c = tid + 256 * i;
        const float v = (x[i] - mu) * rstd * g[c] + beta[c];
        outf[rb + c] = v;
        if constexpr (WB16) outb[rb + c] = __float2bfloat16(v);
    }
}

// ---------------------------------------------------------------------------
extern "C" void kernel_launch(void* const* d_in, const int* in_sizes, int n_in,
                              void* d_out, int out_size, void* d_ws, size_t ws_size,
                              hipStream_t stream) {
    const float* x     = (const float*)d_in[0];
    const float* Wq    = (const float*)d_in[1];
    const float* bq    = (const float*)d_in[2];
    const float* Wk    = (const float*)d_in[3];
    const float* bk    = (const float*)d_in[4];
    const float* Wv    = (const float*)d_in[5];
    const float* bv    = (const float*)d_in[6];
    const float* Wo    = (const float*)d_in[7];
    const float* bo    = (const float*)d_in[8];
    const float* ln1_g = (const float*)d_in[9];
    const float* ln1_b = (const float*)d_in[10];
    const float* W1    = (const float*)d_in[11];
    const float* b1    = (const float*)d_in[12];
    const float* W2    = (const float*)d_in[13];
    const float* b2    = (const float*)d_in[14];
    const float* ln2_g = (const float*)d_in[15];
    const float* ln2_b = (const float*)d_in[16];

    float* out = (float*)d_out;

    // --- workspace arena (bytes) ---
    char* wsb = (char*)d_ws;
    const size_t TCb16 = (size_t)T_SEQ * C_DIM * 2;          // 6,291,456
    const size_t TCf32 = (size_t)T_SEQ * C_DIM * 4;          // 12,582,912
    __hip_bfloat16* xb  = (__hip_bfloat16*)(wsb);
    __hip_bfloat16* qb  = (__hip_bfloat16*)(wsb + TCb16);
    __hip_bfloat16* kb  = (__hip_bfloat16*)(wsb + 2 * TCb16);
    __hip_bfloat16* vtb = (__hip_bfloat16*)(wsb + 3 * TCb16);
    __hip_bfloat16* mid = (__hip_bfloat16*)(wsb);            // [T][F] bf16 overlays 0..25.2MB
    float* proj0 = (float*)(wsb + 4 * TCb16);                // f32 [T][C], split-K slice 0
    float* proj1 = (float*)(wsb + 4 * TCb16 + TCf32);        // slice 1
    __hip_bfloat16* vb = (__hip_bfloat16*)proj0;             // V row-major (dead before proj write)
    float* mlpo0 = proj0;                                    // reuse after add_ln1
    float* mlpo1 = proj1;
    __hip_bfloat16* obuf = (__hip_bfloat16*)(wsb + 4 * TCb16 + 2 * TCf32);
    __hip_bfloat16* hb   = obuf;                             // reuse after proj
    float* hbuf = (float*)(wsb + 4 * TCb16 + 2 * TCf32 + TCb16);
    char* we = wsb + 4 * TCb16 + 2 * TCf32 + TCb16 + TCf32;
    __hip_bfloat16* Wqkv_t = (__hip_bfloat16*)(we);                       // [2304][768]
    __hip_bfloat16* Wo_t   = (__hip_bfloat16*)(we + 3538944);             // [768][768]
    __hip_bfloat16* W1_t   = (__hip_bfloat16*)(we + 3538944 + 1179648);   // [3072][768]
    __hip_bfloat16* W2_t   = (__hip_bfloat16*)(we + 3538944 + 1179648 + 4718592); // [768][3072]
    float* bqkv            = (float*)(we + 3538944 + 1179648 + 2 * 4718592);

    const dim3 blk256(256);

    // --- all prep in one launch ---
    prep_all<<<dim3(4803), blk256, 0, stream>>>(Wq, Wk, Wv, Wo, W1, W2, x, bq, bk, bv,
                                                Wqkv_t, Wo_t, W1_t, W2_t, xb, bqkv);

    // --- fused QKV GEMM (XCD-swizzled): q/k/v row-major out ---
    gemm_mfma<2, 128, 128, 1, true><<<dim3(18, 32), blk256, 0, stream>>>(
        xb, Wqkv_t, bqkv, nullptr, qb, kb, vb, T_SEQ, 3 * C_DIM, C_DIM);

    // --- V transpose: vb [T][C] -> vtb [C][T] ---
    transpose_v<<<dim3(T_SEQ / 64, C_DIM / 64), blk256, 0, stream>>>(vb, vtb);

    // --- flash attention ---
    attn_mfma<<<dim3(N_HEADS, T_SEQ / QBLK), blk256, 0, stream>>>(qb, kb, vtb, obuf);

    // --- output projection, 64x64, split-K=2 -> proj0/proj1 ---
    gemm_mfma<0, 64, 64, 2, false><<<dim3(12, 64, 2), blk256, 0, stream>>>(
        obuf, Wo_t, bo, proj0, nullptr, nullptr, nullptr, T_SEQ, C_DIM, C_DIM);

    // --- h = LN(x + proj0 + proj1): f32 + bf16 ---
    add_ln<true><<<dim3(T_SEQ), blk256, 0, stream>>>(x, proj0, proj1, ln1_g, ln1_b, hbuf, hb);

    // --- MLP1: gelu(h @ W1 + b1) -> bf16 mid (XCD-swizzled) ---
    gemm_mfma<1, 128, 128, 1, true><<<dim3(24, 32), blk256, 0, stream>>>(
        hb, W1_t, b1, nullptr, mid, nullptr, nullptr, T_SEQ, F_DIM, C_DIM);

    // --- MLP2: mid @ W2 + b2, 64x64, split-K=2 -> mlpo0/mlpo1 ---
    gemm_mfma<0, 64, 64, 2, false><<<dim3(12, 64, 2), blk256, 0, stream>>>(
        mid, W2_t, b2, mlpo0, nullptr, nullptr, nullptr, T_SEQ, C_DIM, F_DIM);

    // --- y = LN(h + mlpo0 + mlpo1) ---
    add_ln<false><<<dim3(T_SEQ), blk256, 0, stream>>>(hbuf, mlpo0, mlpo1, ln2_g, ln2_b, out, nullptr);
}